// Round 3
// baseline (228.435 us; speedup 1.0000x reference)
//
#include <hip/hip_runtime.h>

// ---------- types ----------
typedef _Float16 f16;
typedef _Float16 f16x4 __attribute__((ext_vector_type(4)));
typedef _Float16 f16x8 __attribute__((ext_vector_type(8)));
typedef float    f32x4 __attribute__((ext_vector_type(4)));

#define N_ROWS 100000
#define RT 1563           // 1563 * 64 = 100032 padded rows
#define LSX 40            // X tile f16 row stride
#define LSH1 136
#define LSH2 72

// ws: weights only
#define W1T_OFF 0
#define W1T_BYTES (256 * 256 * 2)
#define W2T_OFF W1T_BYTES

// arena (bytes): Xs dbuf only (W1 read direct from L2); h1s/h2s overlay after P1
#define XS0 0
#define XS1 5120
#define ARENA 26624
#define H1S 0             // 64*136*2 = 17408
#define H2S 17408         // 64*72*2  =  9216  -> 26624 == ARENA

// ---------- prep: combined, transposed f16 weights ----------
__global__ void prep_w(const float* __restrict__ wz1, const float* __restrict__ wh1,
                       const float* __restrict__ wz2, const float* __restrict__ wh2,
                       f16* __restrict__ W1T, f16* __restrict__ W2T) {
    const int b = blockIdx.x;
    if (b < 256) {
        int idx = b * 256 + threadIdx.x;
        int k = idx >> 8, c = idx & 255;
        const float* w = (c < 128) ? wz1 : wh1;
        int cc = c & 127;
        W1T[c * 256 + k] = (f16)(w[k * 128 + cc] + w[384 * 128 + k * 128 + cc]);
    } else {
        int idx = (b - 256) * 256 + threadIdx.x;
        int k = idx >> 7, c = idx & 127;
        const float* w = (c < 64) ? wz2 : wh2;
        int cc = c & 63;
        W2T[c * 128 + k] = (f16)(w[k * 64 + cc] + w[192 * 64 + k * 64 + cc]);
    }
}

// ---------- fused: 64 rows/block; X dbuf in LDS (distance-2 reg prefetch),
// ---------- W1 fragments straight from L2 (distance-1 reg dbuf) ----------
__global__ __launch_bounds__(256, 3) void fused(
    const float* __restrict__ x,
    const f16* __restrict__ W1T, const f16* __restrict__ W2T,
    const float* __restrict__ bz1, const float* __restrict__ bh1,
    const float* __restrict__ bz2, const float* __restrict__ bh2,
    const float* __restrict__ wl1, const float* __restrict__ bl1,
    const float* __restrict__ wl2, const float* __restrict__ bl2,
    float* __restrict__ out)
{
    __shared__ __align__(16) char arena[ARENA];
    const int tid = threadIdx.x, lane = tid & 63, wave = tid >> 6;
    const int ln = lane & 15, quad = lane >> 4;
    const int r0 = blockIdx.x * 64;

    // staging thread mapping (X only)
    const int xr = tid >> 2, xcg = tid & 3;            // X: row, col-group(8 f32)
    int gxr = r0 + xr; if (gxr >= N_ROWS) gxr = N_ROWS - 1;
    const float* xp = x + (size_t)gxr * 256 + (xcg << 3);

    // P1 wave tiles: z m-tiles {2w,2w+1}, h {2w+8,2w+9}; n-tiles 0..3 (16 rows each)
    const int Mz = 2 * wave;

    // W1 A-fragment base pointers (LDS round-trip in the staged version returned
    // W1T[(M*16+ln)*256 + it*32 + quad*8 + j] — read direct instead).
    const f16* wb[4];
#pragma unroll
    for (int mi = 0; mi < 4; ++mi) {
        const int M = (mi < 2) ? (Mz + mi) : (8 + Mz + mi - 2);
        wb[mi] = W1T + (size_t)(M * 16 + ln) * 256 + quad * 8;
    }

    f32x4 acc[4][4];                                   // [mi][nt]
#pragma unroll
    for (int a = 0; a < 4; ++a)
#pragma unroll
        for (int b = 0; b < 4; ++b) acc[a][b] = (f32x4){0.f, 0.f, 0.f, 0.f};

    // X prefetch: two register sets, distance 2 (HBM latency ~900cy > 1 iter of work)
    float4 pxa0, pxb0, pxa1, pxb1;
    f16x8 afp[4], afn[4];                              // W A-frag dbuf, distance 1 (L2-hit)

    pxa0 = *(const float4*)(xp + 0);  pxb0 = *(const float4*)(xp + 4);
    pxa1 = *(const float4*)(xp + 32); pxb1 = *(const float4*)(xp + 36);
#pragma unroll
    for (int mi = 0; mi < 4; ++mi) afp[mi] = *(const f16x8*)(wb[mi]);

#pragma unroll
    for (int it = 0; it < 8; ++it) {
        f16* XsB = (f16*)(arena + ((it & 1) ? XS1 : XS0));
        // commit X set (it&1) — holds chunk it's data
        const float4 ca = (it & 1) ? pxa1 : pxa0;
        const float4 cb = (it & 1) ? pxb1 : pxb0;
        *(f16x8*)&XsB[xr * LSX + (xcg << 3)] =
            (f16x8){(f16)ca.x,(f16)ca.y,(f16)ca.z,(f16)ca.w,
                    (f16)cb.x,(f16)cb.y,(f16)cb.z,(f16)cb.w};
        __syncthreads();
        // refill the just-consumed set with chunk it+2 (lands before commit at it+2)
        if (it < 6) {
            if (it & 1) { pxa1 = *(const float4*)(xp + (it + 2) * 32);
                          pxb1 = *(const float4*)(xp + (it + 2) * 32 + 4); }
            else        { pxa0 = *(const float4*)(xp + (it + 2) * 32);
                          pxb0 = *(const float4*)(xp + (it + 2) * 32 + 4); }
        }
        if (it < 7) {
#pragma unroll
            for (int mi = 0; mi < 4; ++mi)
                afn[mi] = *(const f16x8*)(wb[mi] + (it + 1) * 32);
        }
        __builtin_amdgcn_sched_barrier(0);             // pin prefetch issue here

        f16x8 bf[4];
#pragma unroll
        for (int nt = 0; nt < 4; ++nt)
            bf[nt] = *(const f16x8*)&XsB[(16 * nt + ln) * LSX + quad * 8];
#pragma unroll
        for (int mi = 0; mi < 4; ++mi)
#pragma unroll
            for (int nt = 0; nt < 4; ++nt)
                acc[mi][nt] = __builtin_amdgcn_mfma_f32_16x16x32_f16(afp[mi], bf[nt], acc[mi][nt], 0, 0, 0);
#pragma unroll
        for (int mi = 0; mi < 4; ++mi) afp[mi] = afn[mi];
    }
    __syncthreads();                                   // K-loop done; arena reused below

    // prefetch W2 frags (z col 16w+ln, h col 64+16w+ln) -- fly during epilogue
    f16x8 w2f[2][4];
#pragma unroll
    for (int kc = 0; kc < 4; ++kc) {
        w2f[0][kc] = *(const f16x8*)(W2T + (size_t)(16 * wave + ln) * 128 + kc * 32 + quad * 8);
        w2f[1][kc] = *(const f16x8*)(W2T + (size_t)(64 + 16 * wave + ln) * 128 + kc * 32 + quad * 8);
    }

    // P1 epilogue: gates -> h1s. D: col(ln)=X row, row(4quad+i)=W col.
    f16* h1s = (f16*)(arena + H1S);
#pragma unroll
    for (int mi = 0; mi < 2; ++mi) {
        const int jg0 = 32 * wave + 16 * mi + (quad << 2);
        const float4 zb = *(const float4*)(bz1 + jg0);
        const float4 hb = *(const float4*)(bh1 + jg0);
#pragma unroll
        for (int nt = 0; nt < 4; ++nt) {
            const int row = 16 * nt + ln;
            f16x4 pk;
#pragma unroll
            for (int i = 0; i < 4; ++i) {
                float zp = acc[mi][nt][i]     + (&zb.x)[i];
                float hp = acc[mi + 2][nt][i] + (&hb.x)[i];
                float ex = __expf(2.0f * hp);
                float th = 1.0f - 2.0f / (ex + 1.0f);      // tanh
                float sg = 1.0f / (1.0f + __expf(zp));     // 1 - sigmoid
                pk[i] = (f16)fmaxf(th * sg, 0.0f);
            }
            *(f16x4*)&h1s[row * LSH1 + jg0] = pk;
        }
    }
    __syncthreads();

    // ---- P2: h2 = gates(h1 @ W2); wave w: z-tile w, h-tile w+4 ----
    f32x4 acc2[2][4];
#pragma unroll
    for (int a = 0; a < 2; ++a)
#pragma unroll
        for (int b = 0; b < 4; ++b) acc2[a][b] = (f32x4){0.f, 0.f, 0.f, 0.f};
#pragma unroll
    for (int kc = 0; kc < 4; ++kc) {
        f16x8 bf[4];
#pragma unroll
        for (int nt = 0; nt < 4; ++nt)
            bf[nt] = *(const f16x8*)&h1s[(16 * nt + ln) * LSH1 + kc * 32 + quad * 8];
#pragma unroll
        for (int m = 0; m < 2; ++m)
#pragma unroll
            for (int nt = 0; nt < 4; ++nt)
                acc2[m][nt] = __builtin_amdgcn_mfma_f32_16x16x32_f16(w2f[m][kc], bf[nt], acc2[m][nt], 0, 0, 0);
    }
    __syncthreads();                                   // h1s reads done before h2s overlay

    f16* h2s = (f16*)(arena + H2S);
    {
        const int jg0 = 16 * wave + (quad << 2);
        const float4 zb = *(const float4*)(bz2 + jg0);
        const float4 hb = *(const float4*)(bh2 + jg0);
#pragma unroll
        for (int nt = 0; nt < 4; ++nt) {
            const int row = 16 * nt + ln;
            f16x4 pk;
#pragma unroll
            for (int i = 0; i < 4; ++i) {
                float zp = acc2[0][nt][i] + (&zb.x)[i];
                float hp = acc2[1][nt][i] + (&hb.x)[i];
                float ex = __expf(2.0f * hp);
                float th = 1.0f - 2.0f / (ex + 1.0f);
                float sg = 1.0f / (1.0f + __expf(zp));
                pk[i] = (f16)fmaxf(th * sg, 0.0f);
            }
            *(f16x4*)&h2s[row * LSH2 + jg0] = pk;
        }
    }
    __syncthreads();

    // ---- P3: out = relu(h2 @ wl1 + bl1) @ wl2 + bl2 ----
    const float blv = bl1[ln], wlv = wl2[ln], bl2v = bl2[0];
    f16x8 bfr[2];
#pragma unroll
    for (int kc = 0; kc < 2; ++kc)
#pragma unroll
        for (int j = 0; j < 8; ++j)
            bfr[kc][j] = (f16)wl1[(32 * kc + 8 * quad + j) * 16 + ln];

    f32x4 acc3 = (f32x4){0.f, 0.f, 0.f, 0.f};
#pragma unroll
    for (int kc = 0; kc < 2; ++kc) {
        f16x8 af = *(const f16x8*)&h2s[(16 * wave + ln) * LSH2 + kc * 32 + quad * 8];
        acc3 = __builtin_amdgcn_mfma_f32_16x16x32_f16(af, bfr[kc], acc3, 0, 0, 0);
    }
#pragma unroll
    for (int i = 0; i < 4; ++i) {
        float v = fmaxf(acc3[i] + blv, 0.0f) * wlv;
        v += __shfl_xor(v, 1);
        v += __shfl_xor(v, 2);
        v += __shfl_xor(v, 4);
        v += __shfl_xor(v, 8);
        if (ln == 0) {
            const int row = r0 + 16 * wave + (quad << 2) + i;
            if (row < N_ROWS) out[row] = v + bl2v;
        }
    }
}

// ---------- launch ----------
extern "C" void kernel_launch(void* const* d_in, const int* in_sizes, int n_in,
                              void* d_out, int out_size, void* d_ws, size_t ws_size,
                              hipStream_t stream) {
    const float* x   = (const float*)d_in[0];
    const float* wz1 = (const float*)d_in[3];
    const float* bz1 = (const float*)d_in[4];
    const float* wh1 = (const float*)d_in[7];
    const float* bh1 = (const float*)d_in[8];
    const float* wz2 = (const float*)d_in[9];
    const float* bz2 = (const float*)d_in[10];
    const float* wh2 = (const float*)d_in[13];
    const float* bh2 = (const float*)d_in[14];
    const float* wl1 = (const float*)d_in[15];
    const float* bl1 = (const float*)d_in[16];
    const float* wl2 = (const float*)d_in[17];
    const float* bl2 = (const float*)d_in[18];

    char* ws = (char*)d_ws;
    f16* W1T = (f16*)(ws + W1T_OFF);
    f16* W2T = (f16*)(ws + W2T_OFF);
    float* out = (float*)d_out;

    prep_w<<<320, 256, 0, stream>>>(wz1, wh1, wz2, wh2, W1T, W2T);
    fused<<<RT, 256, 0, stream>>>(x, W1T, W2T, bz1, bh1, bz2, bh2,
                                  wl1, bl1, wl2, bl2, out);
}